// Round 2
// baseline (75.077 us; speedup 1.0000x reference)
//
#include <hip/hip_runtime.h>
#include <math.h>

#define MGEMM 3072   // 512 h-groups * 6 kept m-rows
#define KGEMM 512
#define NJ    6      // j = 2..7
#define MK    (MGEMM * KGEMM)
#define OB_PITCH 36  // Obuf row pitch (32 cols padded to 36 to spread LDS banks)
#define OB_PLANE (96 * OB_PITCH)

typedef __attribute__((ext_vector_type(8))) __bf16 bf16x8;
typedef __attribute__((ext_vector_type(4))) float  f32x4;

__device__ __forceinline__ unsigned short f2bf(float f) {
  union { float f; unsigned u; } v; v.f = f;
  unsigned r = v.u + 0x7fffu + ((v.u >> 16) & 1u);   // RNE
  return (unsigned short)(r >> 16);
}
__device__ __forceinline__ float bf2f(unsigned short s) {
  union { unsigned u; float f; } v; v.u = ((unsigned)s) << 16;
  return v.f;
}

// 8-point DCT-II matrix (orthonormal), rows m, cols i.
__device__ const float DBC[8][8] = {
  { 0.35355339f,  0.35355339f,  0.35355339f,  0.35355339f,  0.35355339f,  0.35355339f,  0.35355339f,  0.35355339f},
  { 0.49039264f,  0.41573481f,  0.27778512f,  0.09754516f, -0.09754516f, -0.27778512f, -0.41573481f, -0.49039264f},
  { 0.46193977f,  0.19134172f, -0.19134172f, -0.46193977f, -0.46193977f, -0.19134172f,  0.19134172f,  0.46193977f},
  { 0.41573481f, -0.09754516f, -0.49039264f, -0.27778512f,  0.27778512f,  0.49039264f,  0.09754516f, -0.41573481f},
  { 0.35355339f, -0.35355339f, -0.35355339f,  0.35355339f,  0.35355339f, -0.35355339f, -0.35355339f,  0.35355339f},
  { 0.27778512f, -0.49039264f,  0.09754516f,  0.41573481f, -0.41573481f, -0.09754516f,  0.49039264f, -0.27778512f},
  { 0.19134172f, -0.46193977f,  0.46193977f, -0.19134172f, -0.19134172f,  0.46193977f, -0.46193977f,  0.19134172f},
  { 0.09754516f, -0.27778512f,  0.41573481f, -0.49039264f,  0.49039264f, -0.41573481f,  0.27778512f, -0.09754516f}
};

// ---------------- 1) Dw table: dw[k][w] = bf16( scale(k) * cos(pi*(2w+1)*k/1024) )
// Exact integer angle reduction: cos(pi*n/1024), n = k*(2w+1) mod 2048 -> small-arg fast cos.
__global__ __launch_bounds__(256) void build_dw(unsigned short* __restrict__ dw) {
  int idx = blockIdx.x * 256 + threadIdx.x;       // 512*512
  int k = idx >> 9, w = idx & 511;
  int n = (k * (2 * w + 1)) & 2047;
  float ang = (float)n * 0.0030679615757712823f;  // pi/1024
  float c = __cosf(ang);
  float scale = (k == 0) ? 0.04419417382415922f : 0.0625f;  // sqrt(1/512), sqrt(2/512)
  dw[idx] = f2bf(c * scale);
}

// ---------------- 2) pack: q=floor(255x), apply Db rows m=2..7, split by j=2..7
// zc[j-2][h*6+(m-2)][w] bf16, each matrix 3072x512 contiguous.
__global__ __launch_bounds__(256) void pack_z(const float* __restrict__ x,
                                              unsigned short* __restrict__ zc) {
  const int h  = blockIdx.x;                 // 0..511
  const int t  = threadIdx.x;                // 0..255
  const int c0 = blockIdx.y * 2048 + t * 8;  // 8 consecutive cols = one w, all j
  const float* xb = x + (size_t)(h * 8) * 4096 + c0;
  float q[8][8];
#pragma unroll
  for (int i = 0; i < 8; ++i) {
    float4 a = *reinterpret_cast<const float4*>(xb + (size_t)i * 4096);
    float4 b = *reinterpret_cast<const float4*>(xb + (size_t)i * 4096 + 4);
    q[i][0] = floorf(a.x * 255.0f); q[i][1] = floorf(a.y * 255.0f);
    q[i][2] = floorf(a.z * 255.0f); q[i][3] = floorf(a.w * 255.0f);
    q[i][4] = floorf(b.x * 255.0f); q[i][5] = floorf(b.y * 255.0f);
    q[i][6] = floorf(b.z * 255.0f); q[i][7] = floorf(b.w * 255.0f);
  }
  const int w0 = c0 >> 3;
#pragma unroll
  for (int m = 2; m < 8; ++m) {
    const size_t rowoff = (size_t)(h * 6 + (m - 2)) * KGEMM + w0;
#pragma unroll
    for (int j = 2; j < 8; ++j) {
      float s = 0.0f;
#pragma unroll
      for (int i = 0; i < 8; ++i) s = fmaf(DBC[m][i], q[i][j], s);
      zc[(size_t)(j - 2) * MK + rowoff] = f2bf(s);   // 64 lanes -> 128B contiguous per (m,j)
    }
  }
}

// ---------------- 3) fused GEMM + interleave
// Block: mt (16 h-groups = 96 compact rows = 128 out rows) x nt (32 k = 256 out cols).
// Loops j=2..7; each j's K-loop (K=512, BK=64) double-buffered; C-tile -> LDS Obuf;
// final epilogue writes the whole 128x512B out region coalesced (incl. mask zeros).
__device__ __forceinline__ void gload16(const unsigned short* g, unsigned short* l) {
  __builtin_amdgcn_global_load_lds(
      (__attribute__((address_space(1))) void*)(g),
      (__attribute__((address_space(3))) void*)(l),
      16, 0, 0);
}

__global__ __launch_bounds__(256) void fused_dct(const unsigned short* __restrict__ zc,
                                                 const unsigned short* __restrict__ dw,
                                                 float* __restrict__ out) {
  const int bid = blockIdx.x;        // bid = nt*32 + mt: same-mt blocks share XCD (bid%8==mt%8)
  const int mt  = bid & 31;          // 0..31
  const int nt  = bid >> 5;          // 0..15

  __shared__ unsigned short Ash[2][96 * 64];   // 24 KB
  __shared__ unsigned short Bsh[2][32 * 64];   //  8 KB
  __shared__ unsigned short Obuf[NJ * OB_PLANE]; // ~40.5 KB

  const int tid  = threadIdx.x;
  const int lane = tid & 63;
  const int wv   = tid >> 6;
  const int wm   = wv & 1;    // M-half (48 rows)
  const int wn   = wv >> 1;   // N-half (16 cols)

  f32x4 acc[3] = {};

  // ---- K-loop over flattened (j2, kko), 2-phase double buffer
#define STAGE(buf, j2s, kkos)                                                        \
  do {                                                                               \
    _Pragma("unroll")                                                                \
    for (int q_ = 0; q_ < 3; ++q_) {                                                 \
      const int c_ = wv * 3 + q_;                                                    \
      const int row_ = c_ * 8 + (lane >> 3);                                         \
      gload16(zc + (size_t)(j2s) * MK + (size_t)(mt * 96 + row_) * 512 +             \
                  (kkos) * 64 + (lane & 7) * 8,                                      \
              &Ash[buf][c_ * 512 + lane * 8]);                                       \
    }                                                                                \
    {                                                                                \
      const int rowb_ = wv * 8 + (lane >> 3);                                        \
      gload16(dw + (size_t)(nt * 32 + rowb_) * 512 + (kkos) * 64 + (lane & 7) * 8,   \
              &Bsh[buf][wv * 512 + lane * 8]);                                       \
    }                                                                                \
  } while (0)

  STAGE(0, 0, 0);
  __syncthreads();
  int cur = 0;
  for (int t = 0; t < 48; ++t) {
    const int j2 = t >> 3, kko = t & 7;
    if (t < 47) {
      const int tn = t + 1;
      STAGE(cur ^ 1, tn >> 3, tn & 7);
    }
#pragma unroll
    for (int ks = 0; ks < 2; ++ks) {
      const int ko = ks * 32 + (lane >> 4) * 8;
      const bf16x8 bfr = *reinterpret_cast<const bf16x8*>(
          &Bsh[cur][(wn * 16 + (lane & 15)) * 64 + ko]);
#pragma unroll
      for (int fm = 0; fm < 3; ++fm) {
        const bf16x8 afr = *reinterpret_cast<const bf16x8*>(
            &Ash[cur][(wm * 48 + fm * 16 + (lane & 15)) * 64 + ko]);
        acc[fm] = __builtin_amdgcn_mfma_f32_16x16x32_bf16(afr, bfr, acc[fm], 0, 0, 0);
      }
    }
    if (kko == 7) {   // j finished: C-tile -> Obuf plane j2, reset acc
      const int col = wn * 16 + (lane & 15);
#pragma unroll
      for (int fm = 0; fm < 3; ++fm) {
#pragma unroll
        for (int p = 0; p < 4; ++p) {
          const int row96 = wm * 48 + fm * 16 + (lane >> 4) * 4 + p;
          Obuf[j2 * OB_PLANE + row96 * OB_PITCH + col] = f2bf(acc[fm][p]);
        }
        acc[fm] = (f32x4){0.0f, 0.0f, 0.0f, 0.0f};
      }
    }
    __syncthreads();
    cur ^= 1;
  }
#undef STAGE

  // ---- final epilogue: 128 rows x 512 cols f32, fully coalesced, zeros included
  float* outb = out + (size_t)(mt * 128) * 4096 + nt * 256;
  for (int it = 0; it < 32; ++it) {
    const int v = it * 256 + tid;          // 0..8191 vec4s
    const int row128 = v >> 6;             // 64 vec4 per 256-col row
    const int c4 = (v & 63) << 2;
    f32x4 val = {0.0f, 0.0f, 0.0f, 0.0f};
    const int m = row128 & 7;
    if (m >= 2) {
      const int row96 = (row128 >> 3) * 6 + (m - 2);
      const int kk = c4 >> 3, jb = c4 & 4;
#pragma unroll
      for (int e = 0; e < 4; ++e) {
        const int j = jb + e;
        if (j >= 2)
          val[e] = bf2f(Obuf[(j - 2) * OB_PLANE + row96 * OB_PITCH + kk]);
      }
    }
    *reinterpret_cast<f32x4*>(outb + (size_t)row128 * 4096 + c4) = val;
  }
}

extern "C" void kernel_launch(void* const* d_in, const int* in_sizes, int n_in,
                              void* d_out, int out_size, void* d_ws, size_t ws_size,
                              hipStream_t stream) {
  const float* x = (const float*)d_in[0];
  float* out = (float*)d_out;
  char* ws = (char*)d_ws;

  unsigned short* dw = (unsigned short*)ws;             // 512 KB
  unsigned short* zc = (unsigned short*)(ws + 524288);  // 18.87 MB

  build_dw<<<1024, 256, 0, stream>>>(dw);
  pack_z<<<dim3(512, 2), 256, 0, stream>>>(x, zc);
  fused_dct<<<512, 256, 0, stream>>>(zc, dw, out);
}

// Round 3
// 57.690 us; speedup vs baseline: 1.3014x; 1.3014x over previous
//
#include <hip/hip_runtime.h>
#include <math.h>

// zc_t layout: [j2(6)*16 + kko][3072 rows][32 w] bf16, chunk-swizzled: logical
// 8-elem chunk g of row r stored at chunk (g ^ ((r>>1)&3)). Slab = 98304 elems.
// dw_t layout: [kko(16)][512 k][32 w] bf16, same swizzle keyed on k.
#define ZSLAB 98304
#define DSLAB 16384

typedef __attribute__((ext_vector_type(8))) __bf16 bf16x8;
typedef __attribute__((ext_vector_type(4))) float  f32x4;

__device__ __forceinline__ unsigned short f2bf(float f) {
  union { float f; unsigned u; } v; v.f = f;
  unsigned r = v.u + 0x7fffu + ((v.u >> 16) & 1u);   // RNE
  return (unsigned short)(r >> 16);
}
__device__ __forceinline__ float bf2f(unsigned short s) {
  union { unsigned u; float f; } v; v.u = ((unsigned)s) << 16;
  return v.f;
}

__device__ const float DBC[8][8] = {
  { 0.35355339f,  0.35355339f,  0.35355339f,  0.35355339f,  0.35355339f,  0.35355339f,  0.35355339f,  0.35355339f},
  { 0.49039264f,  0.41573481f,  0.27778512f,  0.09754516f, -0.09754516f, -0.27778512f, -0.41573481f, -0.49039264f},
  { 0.46193977f,  0.19134172f, -0.19134172f, -0.46193977f, -0.46193977f, -0.19134172f,  0.19134172f,  0.46193977f},
  { 0.41573481f, -0.09754516f, -0.49039264f, -0.27778512f,  0.27778512f,  0.49039264f,  0.09754516f, -0.41573481f},
  { 0.35355339f, -0.35355339f, -0.35355339f,  0.35355339f,  0.35355339f, -0.35355339f, -0.35355339f,  0.35355339f},
  { 0.27778512f, -0.49039264f,  0.09754516f,  0.41573481f, -0.41573481f, -0.09754516f,  0.49039264f, -0.27778512f},
  { 0.19134172f, -0.46193977f,  0.46193977f, -0.19134172f, -0.19134172f,  0.46193977f, -0.46193977f,  0.19134172f},
  { 0.09754516f, -0.27778512f,  0.41573481f, -0.49039264f,  0.49039264f, -0.41573481f,  0.27778512f, -0.09754516f}
};

// ---------------- 1) Dw table, tiled+swizzled
__global__ __launch_bounds__(256) void build_dw(unsigned short* __restrict__ dw) {
  int idx = blockIdx.x * 256 + threadIdx.x;       // 512*512
  int k = idx >> 9, w = idx & 511;
  int n = (k * (2 * w + 1)) & 2047;
  float c = __cosf((float)n * 0.0030679615757712823f);  // pi/1024, exact int reduction
  float scale = (k == 0) ? 0.04419417382415922f : 0.0625f;
  const int kko = w >> 5, g = (w >> 3) & 3, e = w & 7, s = (k >> 1) & 3;
  dw[(size_t)kko * DSLAB + k * 32 + ((g ^ s) << 3) + e] = f2bf(c * scale);
}

// ---------------- 2) pack: q=floor(255x), Db rows m=2..7, emit zc_t swizzled
__global__ __launch_bounds__(256) void pack_z(const float* __restrict__ x,
                                              unsigned short* __restrict__ zc) {
  const int h  = blockIdx.x;                 // 0..511
  const int t  = threadIdx.x;                // 0..255
  const int c0 = blockIdx.y * 2048 + t * 8;  // this thread's 8 cols = one w
  const float* xb = x + (size_t)(h * 8) * 4096 + c0;
  float q[8][8];
#pragma unroll
  for (int i = 0; i < 8; ++i) {
    float4 a = *reinterpret_cast<const float4*>(xb + (size_t)i * 4096);
    float4 b = *reinterpret_cast<const float4*>(xb + (size_t)i * 4096 + 4);
    q[i][0] = floorf(a.x * 255.0f); q[i][1] = floorf(a.y * 255.0f);
    q[i][2] = floorf(a.z * 255.0f); q[i][3] = floorf(a.w * 255.0f);
    q[i][4] = floorf(b.x * 255.0f); q[i][5] = floorf(b.y * 255.0f);
    q[i][6] = floorf(b.z * 255.0f); q[i][7] = floorf(b.w * 255.0f);
  }
  const int w0 = c0 >> 3;
  const int kko = w0 >> 5, g = (w0 >> 3) & 3, e = w0 & 7;
#pragma unroll
  for (int m = 2; m < 8; ++m) {
    const int row = h * 6 + (m - 2);
    const int s = (row >> 1) & 3;
    const size_t base = (size_t)row * 32 + ((g ^ s) << 3) + e;
#pragma unroll
    for (int j = 2; j < 8; ++j) {
      float v = 0.0f;
#pragma unroll
      for (int i = 0; i < 8; ++i) v = fmaf(DBC[m][i], q[i][j], v);
      zc[(size_t)((j - 2) * 16 + kko) * ZSLAB + base] = f2bf(v);
    }
  }
}

// ---------------- 3) fused batched-GEMM + interleave
// Block (mt 0..31, nt 0..15): out rows [mt*128,+128), out cols [nt*256,+256).
// 6 waves, wave wv owns j = wv+2: GEMM M=96, N=32 (6x2 frags), K=512, BK=32.
__device__ __forceinline__ void gload16(const unsigned short* g, unsigned short* l) {
  __builtin_amdgcn_global_load_lds(
      (__attribute__((address_space(1))) void*)(g),
      (__attribute__((address_space(3))) void*)(l),
      16, 0, 0);
}

__global__ __launch_bounds__(384) void fused_dct(const unsigned short* __restrict__ zc,
                                                 const unsigned short* __restrict__ dw,
                                                 float* __restrict__ out) {
  const int bid = blockIdx.x;       // bid = nt*32 + mt -> bid%8 = mt%8: same-mt same XCD
  const int mt  = bid & 31;
  const int nt  = bid >> 5;

  // Union: phases are barrier-separated. A dbuf 72KB + B dbuf 4KB = 76KB; Obuf 38.25KB.
  __shared__ __align__(16) unsigned char SM[77824];
  unsigned short* AshB = (unsigned short*)SM;            // [2][6*3072]
  unsigned short* BshB = (unsigned short*)(SM + 73728);  // [2][1024]
  unsigned short* Obuf = (unsigned short*)SM;            // [6][96*34]

  const int tid  = threadIdx.x;
  const int lane = tid & 63;
  const int wv   = tid >> 6;          // 0..5 = j-2
  const int l15  = lane & 15;
  const int swz  = (((lane >> 4) ^ ((lane >> 1) & 3)) << 3);  // swizzled chunk, elems

  f32x4 acc[6][2] = {};

#define STAGE(buf, kkos)                                                          \
  do {                                                                            \
    unsigned short* As_ = AshB + (buf) * 18432;                                   \
    _Pragma("unroll")                                                             \
    for (int q_ = 0; q_ < 6; ++q_)                                                \
      gload16(zc + (size_t)(q_ * 16 + (kkos)) * ZSLAB + mt * 3072 + tid * 8,      \
              As_ + q_ * 3072 + tid * 8);                                         \
    if (tid < 128)                                                                \
      gload16(dw + (size_t)(kkos) * DSLAB + nt * 1024 + tid * 8,                  \
              BshB + (buf) * 1024 + tid * 8);                                     \
  } while (0)

  STAGE(0, 0);
  __syncthreads();                    // compiler drains vmcnt(0) before barrier
  int cur = 0;
  for (int t = 0; t < 16; ++t) {
    if (t < 15) STAGE(cur ^ 1, t + 1);
    const unsigned short* Ap = AshB + cur * 18432 + wv * 3072;
    const unsigned short* Bp = BshB + cur * 1024;
    bf16x8 bfr[2];
#pragma unroll
    for (int nf = 0; nf < 2; ++nf)
      bfr[nf] = *reinterpret_cast<const bf16x8*>(Bp + (nf * 16 + l15) * 32 + swz);
#pragma unroll
    for (int mf = 0; mf < 6; ++mf) {
      const bf16x8 afr = *reinterpret_cast<const bf16x8*>(Ap + (mf * 16 + l15) * 32 + swz);
      acc[mf][0] = __builtin_amdgcn_mfma_f32_16x16x32_bf16(afr, bfr[0], acc[mf][0], 0, 0, 0);
      acc[mf][1] = __builtin_amdgcn_mfma_f32_16x16x32_bf16(afr, bfr[1], acc[mf][1], 0, 0, 0);
    }
    __syncthreads();                  // drains next-stage loads; protects buffer reuse
    cur ^= 1;
  }
#undef STAGE

  // ---- C -> Obuf (plane wv), pitch 34 to spread banks
  unsigned short* Ob = Obuf + wv * 3264;
#pragma unroll
  for (int mf = 0; mf < 6; ++mf)
#pragma unroll
    for (int nf = 0; nf < 2; ++nf)
#pragma unroll
      for (int p = 0; p < 4; ++p)
        Ob[(mf * 16 + (lane >> 4) * 4 + p) * 34 + nf * 16 + l15] = f2bf(acc[mf][nf][p]);
  __syncthreads();

  // ---- epilogue: 128 rows x 256 f32 cols, coalesced f32x4 incl. mask zeros
  float* outb = out + (size_t)(mt * 128) * 4096 + nt * 256;
  for (int v = tid; v < 8192; v += 384) {
    const int row128 = v >> 6;
    const int c4 = (v & 63) << 2;
    f32x4 val = {0.0f, 0.0f, 0.0f, 0.0f};
    const int m = row128 & 7;
    if (m >= 2) {
      const int row96 = (row128 >> 3) * 6 + (m - 2);
      const int kk = c4 >> 3, jb = c4 & 4;
#pragma unroll
      for (int e = 0; e < 4; ++e) {
        const int j = jb + e;
        if (j >= 2)
          val[e] = bf2f(Obuf[(j - 2) * 3264 + row96 * 34 + kk]);
      }
    }
    *reinterpret_cast<f32x4*>(outb + (size_t)row128 * 4096 + c4) = val;
  }
}

extern "C" void kernel_launch(void* const* d_in, const int* in_sizes, int n_in,
                              void* d_out, int out_size, void* d_ws, size_t ws_size,
                              hipStream_t stream) {
  const float* x = (const float*)d_in[0];
  float* out = (float*)d_out;
  char* ws = (char*)d_ws;

  unsigned short* dw = (unsigned short*)ws;             // 512 KB
  unsigned short* zc = (unsigned short*)(ws + 524288);  // 18.87 MB

  build_dw<<<1024, 256, 0, stream>>>(dw);
  pack_z<<<dim3(512, 2), 256, 0, stream>>>(x, zc);
  fused_dct<<<512, 384, 0, stream>>>(zc, dw, out);
}